// Round 10
// baseline (627.502 us; speedup 1.0000x reference)
//
#include <hip/hip_runtime.h>
#include <hip/hip_fp16.h>
#include <math.h>

#define NNODES 20000
#define NEDGES 320000
#define CC 128          // channels
#define TC 384          // 3*C
#define BB 20           // basis dim
#define RCUT_F 5.0f
#define PI_F 3.14159265358979323846f
#define PKF 28          // packed floats per edge (112 B, float4-aligned)

// ---------------------------------------------------------------------------
// CSR build: zero -> histogram -> single-block scan -> pack+scatter
// ---------------------------------------------------------------------------
__global__ __launch_bounds__(256) void zero_counts_kernel(int* __restrict__ counts) {
  const int i = blockIdx.x * 256 + threadIdx.x;
  if (i < NNODES) counts[i] = 0;
}

__global__ __launch_bounds__(256) void hist_kernel(const int* __restrict__ eidx,
                                                   int* __restrict__ counts) {
  const int e = blockIdx.x * 256 + threadIdx.x;
  if (e < NEDGES) atomicAdd(&counts[eidx[e]], 1);
}

__global__ __launch_bounds__(512) void scan_kernel(int* __restrict__ counts,
                                                   int* __restrict__ offsets) {
  __shared__ int sums[512];
  const int t = threadIdx.x;
  const int chunk = 40;                       // ceil(20000/512)
  const int lo = t * chunk;
  const int hi = min(lo + chunk, NNODES);
  int s = 0;
  for (int i = lo; i < hi; ++i) s += counts[i];
  sums[t] = s;
  __syncthreads();
  for (int d = 1; d < 512; d <<= 1) {
    const int other = (t >= d) ? sums[t - d] : 0;
    __syncthreads();
    sums[t] += other;
    __syncthreads();
  }
  int run = sums[t] - s;                      // exclusive prefix
  for (int i = lo; i < hi; ++i) {
    offsets[i] = run;
    run += counts[i];
    counts[i] = 0;                            // re-zero: reused as scatter cursor
  }
  if (hi == NNODES) offsets[NNODES] = run;    // == NEDGES
}

// packed[pos] = { j(bits), fc, v0, v1, v2, fc*attrs[0..19], pad[3] }
// r10: register-built row + 7x float4 stores (was 28 scalar stores) and
// 5x float4 eattr reads (rows are 80 B = 16B-aligned). Fewer VMEM instrs
// in a serialized pre-gather kernel.
__global__ __launch_bounds__(256) void pack_scatter_kernel(
    const int* __restrict__ eidx, const float* __restrict__ ew,
    const float* __restrict__ evers, const float* __restrict__ eattr,
    const int* __restrict__ offsets, int* __restrict__ counts,
    float* __restrict__ packed) {
  const int e = blockIdx.x * 256 + threadIdx.x;
  if (e >= NEDGES) return;
  const int i = eidx[e];
  const int j = eidx[NEDGES + e];
  const int pos = offsets[i] + atomicAdd(&counts[i], 1);
  const float w = ew[e];
  const float fc = (w < RCUT_F)
      ? 0.5f * (cosf(PI_F * (1.0f / RCUT_F) * w) + 1.0f) : 0.0f;
  const float v0 = evers[(size_t)e * 3];
  const float v1 = evers[(size_t)e * 3 + 1];
  const float v2 = evers[(size_t)e * 3 + 2];
  const float4* ae4 = reinterpret_cast<const float4*>(eattr + (size_t)e * BB);
  const float4 a0 = ae4[0], a1 = ae4[1], a2 = ae4[2], a3 = ae4[3], a4 = ae4[4];
  float4* p4 = reinterpret_cast<float4*>(packed + (size_t)pos * PKF);
  p4[0] = make_float4(__int_as_float(j), fc, v0, v1);
  p4[1] = make_float4(v2, fc * a0.x, fc * a0.y, fc * a0.z);
  p4[2] = make_float4(fc * a0.w, fc * a1.x, fc * a1.y, fc * a1.z);
  p4[3] = make_float4(fc * a1.w, fc * a2.x, fc * a2.y, fc * a2.z);
  p4[4] = make_float4(fc * a2.w, fc * a3.x, fc * a3.y, fc * a3.z);
  p4[5] = make_float4(fc * a3.w, fc * a4.x, fc * a4.y, fc * a4.z);
  p4[6] = make_float4(fc * a4.w, 0.0f, 0.0f, 0.0f);
}

// fallback (no packing) scatter for small ws
__global__ __launch_bounds__(256) void scatter_kernel(const int* __restrict__ eidx,
                                                      const int* __restrict__ offsets,
                                                      int* __restrict__ counts,
                                                      int* __restrict__ edge_list) {
  const int e = blockIdx.x * 256 + threadIdx.x;
  if (e < NEDGES) {
    const int i = eidx[e];
    const int pos = offsets[i] + atomicAdd(&counts[i], 1);
    edge_list[pos] = e;
  }
}

// ---------------------------------------------------------------------------
// Context net: x = silu(q@W1 + b1) @ W2 + b2   [N, 3C] (fp16), plus OPTIONAL
// fused fp16 conversion of mu -> muh (CONVERT_MU=1; saves a launch).
// occ_pad: 12 KB LDS pin -> 20 KB total -> 4 waves/SIMD -> VGPR cap 128,
// no spill (allocator model verified r0-r3). r9: ctx_net was healthy anyway;
// pad kept as insurance, costs nothing (grid gives ~10 blk/CU regardless).
// ---------------------------------------------------------------------------
#define CNPB 8
template <int CONVERT_MU>
__global__ __launch_bounds__(128) void ctx_net_kernel(
    const float* __restrict__ q, const float* __restrict__ mu,
    const float* __restrict__ W1, const float* __restrict__ b1,
    const float* __restrict__ W2, const float* __restrict__ b2,
    __half* __restrict__ x, __half* __restrict__ muh) {
  __shared__ __align__(16) float q_lds[CNPB][CC];
  __shared__ __align__(16) float h_lds[CNPB][CC];
  __shared__ __align__(16) float occ_pad[3072];   // 12 KB occupancy pin
  const int t = threadIdx.x;
  const int node0 = blockIdx.x * CNPB;

  #pragma unroll
  for (int n = 0; n < CNPB; ++n)
    q_lds[n][t] = q[(size_t)(node0 + n) * CC + t];

  if (CONVERT_MU) {
    #pragma unroll
    for (int n = 0; n < CNPB; ++n) {
      const size_t mb = (size_t)(node0 + n) * TC;
      muh[mb + t]          = __float2half_rn(mu[mb + t]);
      muh[mb + CC + t]     = __float2half_rn(mu[mb + CC + t]);
      muh[mb + 2 * CC + t] = __float2half_rn(mu[mb + 2 * CC + t]);
    }
  }

  // keep occ_pad live (never taken at runtime; compiler can't prove it)
  if (blockIdx.x == 0x7FFFFFFFu) {
    occ_pad[t] = q[t];
    x[t] = __float2half_rn(occ_pad[t ^ 1]);
  }
  __syncthreads();

  float acc[CNPB];
  {
    const float bv = b1[t];
    #pragma unroll
    for (int n = 0; n < CNPB; ++n) acc[n] = bv;
  }
  for (int k = 0; k < CC; k += 8) {
    float w[8];
    #pragma unroll
    for (int r = 0; r < 8; ++r) w[r] = W1[(size_t)(k + r) * CC + t];
    #pragma unroll
    for (int n = 0; n < CNPB; ++n) {
      const float4 q0 = *reinterpret_cast<const float4*>(&q_lds[n][k]);
      const float4 q1 = *reinterpret_cast<const float4*>(&q_lds[n][k + 4]);
      acc[n] = fmaf(q0.x, w[0], acc[n]); acc[n] = fmaf(q0.y, w[1], acc[n]);
      acc[n] = fmaf(q0.z, w[2], acc[n]); acc[n] = fmaf(q0.w, w[3], acc[n]);
      acc[n] = fmaf(q1.x, w[4], acc[n]); acc[n] = fmaf(q1.y, w[5], acc[n]);
      acc[n] = fmaf(q1.z, w[6], acc[n]); acc[n] = fmaf(q1.w, w[7], acc[n]);
    }
  }
  #pragma unroll
  for (int n = 0; n < CNPB; ++n) {
    const float v = acc[n];
    h_lds[n][t] = v / (1.0f + expf(-v));
  }
  __syncthreads();

  float y0[CNPB], y1[CNPB], y2[CNPB];
  {
    const float bb0 = b2[t], bb1 = b2[CC + t], bb2 = b2[2 * CC + t];
    #pragma unroll
    for (int n = 0; n < CNPB; ++n) { y0[n] = bb0; y1[n] = bb1; y2[n] = bb2; }
  }
  for (int k = 0; k < CC; k += 8) {
    float w0[8], w1[8], w2[8];
    #pragma unroll
    for (int r = 0; r < 8; ++r) {
      const size_t row = (size_t)(k + r) * TC;
      w0[r] = W2[row + t];
      w1[r] = W2[row + CC + t];
      w2[r] = W2[row + 2 * CC + t];
    }
    #pragma unroll
    for (int n = 0; n < CNPB; ++n) {
      const float4 h0 = *reinterpret_cast<const float4*>(&h_lds[n][k]);
      const float4 h1 = *reinterpret_cast<const float4*>(&h_lds[n][k + 4]);
      y0[n] = fmaf(h0.x, w0[0], y0[n]); y0[n] = fmaf(h0.y, w0[1], y0[n]);
      y0[n] = fmaf(h0.z, w0[2], y0[n]); y0[n] = fmaf(h0.w, w0[3], y0[n]);
      y0[n] = fmaf(h1.x, w0[4], y0[n]); y0[n] = fmaf(h1.y, w0[5], y0[n]);
      y0[n] = fmaf(h1.z, w0[6], y0[n]); y0[n] = fmaf(h1.w, w0[7], y0[n]);
      y1[n] = fmaf(h0.x, w1[0], y1[n]); y1[n] = fmaf(h0.y, w1[1], y1[n]);
      y1[n] = fmaf(h0.z, w1[2], y1[n]); y1[n] = fmaf(h0.w, w1[3], y1[n]);
      y1[n] = fmaf(h1.x, w1[4], y1[n]); y1[n] = fmaf(h1.y, w1[5], y1[n]);
      y1[n] = fmaf(h1.z, w1[6], y1[n]); y1[n] = fmaf(h1.w, w1[7], y1[n]);
      y2[n] = fmaf(h0.x, w2[0], y2[n]); y2[n] = fmaf(h0.y, w2[1], y2[n]);
      y2[n] = fmaf(h0.z, w2[2], y2[n]); y2[n] = fmaf(h0.w, w2[3], y2[n]);
      y2[n] = fmaf(h1.x, w2[4], y2[n]); y2[n] = fmaf(h1.y, w2[5], y2[n]);
      y2[n] = fmaf(h1.z, w2[6], y2[n]); y2[n] = fmaf(h1.w, w2[7], y2[n]);
    }
  }
  #pragma unroll
  for (int n = 0; n < CNPB; ++n) {
    const size_t base = (size_t)(node0 + n) * TC;
    x[base + t]          = __float2half_rn(y0[n]);
    x[base + CC + t]     = __float2half_rn(y1[n]);
    x[base + 2 * CC + t] = __float2half_rn(y2[n]);
  }
}

// ---------------------------------------------------------------------------
// Gather (packed path): one block of 384 threads per node; thread c owns
// filter column c (weights in 20 regs). EXACT r5-verified form (177 us).
// Ledger (all A/B'd against this structure, 6 attempts):
//   r3 x2 fp32 = 186 | r4 manual rotate = 294 (vmcnt(0) drains)
//   r5 x2 fp16 = 177 | r6 x4 unroll = 251 (regs can't hold 4 chains)
//   r7 persistent-1280 = 237 (barrier serialization, no oversubscription)
//   r8 muh4 interleave = 200 (FETCH +39MB, grp2 wasn't critical)
// => this is the floor of this structure. DO NOT touch.
// ---------------------------------------------------------------------------
#define GTH 384

struct EdgeRegs { float4 h0, h1, h2, h3, h4, h5, h6; };

__device__ __forceinline__ EdgeRegs load_edge(const float4* __restrict__ p4,
                                              int k) {
  const float4* p = p4 + (size_t)k * (PKF / 4);
  EdgeRegs E;
  E.h0 = p[0]; E.h1 = p[1]; E.h2 = p[2]; E.h3 = p[3];
  E.h4 = p[4]; E.h5 = p[5]; E.h6 = p[6];
  return E;
}

__device__ __forceinline__ float filter_ws(const EdgeRegs& E,
                                           const float* wreg, float bfc) {
  float ws = E.h0.y * bfc;                    // fc * bf[c]
  ws = fmaf(E.h1.y, wreg[0], ws);  ws = fmaf(E.h1.z, wreg[1], ws);
  ws = fmaf(E.h1.w, wreg[2], ws);  ws = fmaf(E.h2.x, wreg[3], ws);
  ws = fmaf(E.h2.y, wreg[4], ws);  ws = fmaf(E.h2.z, wreg[5], ws);
  ws = fmaf(E.h2.w, wreg[6], ws);  ws = fmaf(E.h3.x, wreg[7], ws);
  ws = fmaf(E.h3.y, wreg[8], ws);  ws = fmaf(E.h3.z, wreg[9], ws);
  ws = fmaf(E.h3.w, wreg[10], ws); ws = fmaf(E.h4.x, wreg[11], ws);
  ws = fmaf(E.h4.y, wreg[12], ws); ws = fmaf(E.h4.z, wreg[13], ws);
  ws = fmaf(E.h4.w, wreg[14], ws); ws = fmaf(E.h5.x, wreg[15], ws);
  ws = fmaf(E.h5.y, wreg[16], ws); ws = fmaf(E.h5.z, wreg[17], ws);
  ws = fmaf(E.h5.w, wreg[18], ws); ws = fmaf(E.h6.x, wreg[19], ws);
  return ws;
}

__global__ __launch_bounds__(GTH) void gather_packed_kernel(
    const float* __restrict__ packed,
    const float* __restrict__ Wf, const float* __restrict__ bf,
    const __half* __restrict__ xh, const __half* __restrict__ muh,
    const float* __restrict__ mu_in,
    const float* __restrict__ q_in, const int* __restrict__ offsets,
    float* __restrict__ qout, float* __restrict__ muout) {
  __shared__ float red[3][CC];
  const int c = threadIdx.x;
  const int i = blockIdx.x;
  const int grp = c >> 7;          // wave-uniform
  const int ch = c & 127;

  float wreg[BB];
  #pragma unroll
  for (int b = 0; b < BB; ++b) wreg[b] = Wf[b * TC + c];
  const float bfc = bf[c];

  const float4* p4 = reinterpret_cast<const float4*>(packed);
  const int start = offsets[i];
  const int end = offsets[i + 1];
  float a0 = 0.f, a1 = 0.f, a2 = 0.f;

  int k = start;
  for (; k + 1 < end; k += 2) {
    const EdgeRegs A = load_edge(p4, k);
    const EdgeRegs B = load_edge(p4, k + 1);
    const int jA = __float_as_int(A.h0.x);
    const int jB = __float_as_int(B.h0.x);
    const float xA = __half2float(xh[(size_t)jA * TC + c]);
    const float xB = __half2float(xh[(size_t)jB * TC + c]);
    float muA0, muA1, muA2, muB0, muB1, muB2;
    if (grp == 2) {
      const __half* mA = muh + (size_t)jA * TC + ch;
      const __half* mB = muh + (size_t)jB * TC + ch;
      muA0 = __half2float(mA[0]);
      muA1 = __half2float(mA[CC]);
      muA2 = __half2float(mA[2 * CC]);
      muB0 = __half2float(mB[0]);
      muB1 = __half2float(mB[CC]);
      muB2 = __half2float(mB[2 * CC]);
    }
    const float wsA = filter_ws(A, wreg, bfc);
    const float wsB = filter_ws(B, wreg, bfc);
    const float xvA = xA * wsA;
    const float xvB = xB * wsB;
    if (grp == 0) {
      a0 += xvA + xvB;
    } else if (grp == 1) {
      a0 = fmaf(xvA, A.h0.z, fmaf(xvB, B.h0.z, a0));
      a1 = fmaf(xvA, A.h0.w, fmaf(xvB, B.h0.w, a1));
      a2 = fmaf(xvA, A.h1.x, fmaf(xvB, B.h1.x, a2));
    } else {
      a0 = fmaf(xvA, muA0, fmaf(xvB, muB0, a0));
      a1 = fmaf(xvA, muA1, fmaf(xvB, muB1, a1));
      a2 = fmaf(xvA, muA2, fmaf(xvB, muB2, a2));
    }
  }
  if (k < end) {
    const EdgeRegs A = load_edge(p4, k);
    const int jA = __float_as_int(A.h0.x);
    const float xA = __half2float(xh[(size_t)jA * TC + c]);
    const float wsA = filter_ws(A, wreg, bfc);
    const float xvA = xA * wsA;
    if (grp == 0) {
      a0 += xvA;
    } else if (grp == 1) {
      a0 = fmaf(xvA, A.h0.z, a0);
      a1 = fmaf(xvA, A.h0.w, a1);
      a2 = fmaf(xvA, A.h1.x, a2);
    } else {
      const __half* mA = muh + (size_t)jA * TC + ch;
      a0 = fmaf(xvA, __half2float(mA[0]), a0);
      a1 = fmaf(xvA, __half2float(mA[CC]), a1);
      a2 = fmaf(xvA, __half2float(mA[2 * CC]), a2);
    }
  }

  if (grp == 1) { red[0][ch] = a0; red[1][ch] = a1; red[2][ch] = a2; }
  __syncthreads();

  if (grp == 0) {
    qout[(size_t)i * CC + ch] = q_in[(size_t)i * CC + ch] + a0;
  } else if (grp == 2) {
    const size_t mb = (size_t)i * TC;
    muout[mb + ch]          = mu_in[mb + ch]          + red[0][ch] + a0;
    muout[mb + CC + ch]     = mu_in[mb + CC + ch]     + red[1][ch] + a1;
    muout[mb + 2 * CC + ch] = mu_in[mb + 2 * CC + ch] + red[2][ch] + a2;
  }
}

// fallback gather (edge_list indirection) for small ws
__global__ __launch_bounds__(GTH) void gather_list_kernel(
    const int* __restrict__ eidx, const float* __restrict__ ew,
    const float* __restrict__ evers, const float* __restrict__ eattr,
    const float* __restrict__ Wf, const float* __restrict__ bf,
    const __half* __restrict__ xh, const float* __restrict__ mu_in,
    const float* __restrict__ q_in,
    const int* __restrict__ offsets, const int* __restrict__ edge_list,
    float* __restrict__ qout, float* __restrict__ muout) {
  __shared__ float red[3][CC];
  const int c = threadIdx.x;
  const int i = blockIdx.x;
  const int grp = c >> 7;
  const int ch = c & 127;
  float wreg[BB];
  #pragma unroll
  for (int b = 0; b < BB; ++b) wreg[b] = Wf[b * TC + c];
  const float bfc = bf[c];
  const int start = offsets[i];
  const int end = offsets[i + 1];
  float a0 = 0.f, a1 = 0.f, a2 = 0.f;
  for (int k = start; k < end; ++k) {
    const int e = edge_list[k];
    const int j = eidx[NEDGES + e];
    const float w = ew[e];
    const float fc = (w < RCUT_F)
        ? 0.5f * (cosf(PI_F * (1.0f / RCUT_F) * w) + 1.0f) : 0.0f;
    const float2* ae2 = reinterpret_cast<const float2*>(eattr + (size_t)e * BB);
    float wsum = bfc;
    #pragma unroll
    for (int b = 0; b < BB / 2; ++b) {
      const float2 a = ae2[b];
      wsum = fmaf(a.x, wreg[2 * b], wsum);
      wsum = fmaf(a.y, wreg[2 * b + 1], wsum);
    }
    wsum *= fc;
    const float xv = __half2float(xh[(size_t)j * TC + c]) * wsum;
    if (grp == 0) {
      a0 += xv;
    } else if (grp == 1) {
      const float v0 = evers[(size_t)e * 3];
      const float v1 = evers[(size_t)e * 3 + 1];
      const float v2 = evers[(size_t)e * 3 + 2];
      a0 = fmaf(xv, v0, a0); a1 = fmaf(xv, v1, a1); a2 = fmaf(xv, v2, a2);
    } else {
      const float* muj = mu_in + (size_t)j * TC + ch;
      a0 = fmaf(xv, muj[0], a0);
      a1 = fmaf(xv, muj[CC], a1);
      a2 = fmaf(xv, muj[2 * CC], a2);
    }
  }
  if (grp == 1) { red[0][ch] = a0; red[1][ch] = a1; red[2][ch] = a2; }
  __syncthreads();
  if (grp == 0) {
    qout[(size_t)i * CC + ch] = q_in[(size_t)i * CC + ch] + a0;
  } else if (grp == 2) {
    const size_t mb = (size_t)i * TC;
    muout[mb + ch]          = mu_in[mb + ch]          + red[0][ch] + a0;
    muout[mb + CC + ch]     = mu_in[mb + CC + ch]     + red[1][ch] + a1;
    muout[mb + 2 * CC + ch] = mu_in[mb + 2 * CC + ch] + red[2][ch] + a2;
  }
}

// ---------------------------------------------------------------------------
// Mixing kernel v5: 16 nodes / 256 threads (two 128-thread halves, each owns
// 8 nodes). Rationale: mix streams Wmix/Wm1/Wm2 (448 KB) per block; at
// MNPB=8 that is 2500 x 448 KB = 1.12 GB of L2 weight reads and its r0
// profile (VALU 49%, latency-bound) pointed at the weight stream. Two halves
// issue loads to the SAME weight lines (L1-broadcast) -> per-node weight
// traffic halves (0.56 GB total); per-thread registers/work unchanged.
// LDS 40 KB -> 4 blk/CU x 4 waves = 16 waves/CU = 4 waves/SIMD -> VGPR cap
// 128 >= ~90 needed => no spill (allocator model verified r0-r3).
// ---------------------------------------------------------------------------
#define MNPB 16
#define MNPT 8    // nodes per thread (per half)
__global__ __launch_bounds__(256) void mix_kernel(
    const float* __restrict__ Wmix, const float* __restrict__ Wm1,
    const float* __restrict__ bm1, const float* __restrict__ Wm2,
    const float* __restrict__ bm2, float* __restrict__ qout,
    float* __restrict__ muout) {
  __shared__ __align__(16) float mu_lds[MNPB][3][CC];   // 24 KB
  __shared__ __align__(16) float vn_lds[MNPB][CC];      // 8 KB
  __shared__ __align__(16) float h2_lds[MNPB][CC];      // 8 KB

  const int t = threadIdx.x & 127;          // channel
  const int half = threadIdx.x >> 7;        // which 8-node group
  const int nb = half * MNPT;               // LDS row base for this half
  const int node0 = blockIdx.x * MNPB + nb; // first node for this half

  #pragma unroll
  for (int n = 0; n < MNPT; ++n) {
    const size_t mb = (size_t)(node0 + n) * TC;
    mu_lds[nb + n][0][t] = muout[mb + t];
    mu_lds[nb + n][1][t] = muout[mb + CC + t];
    mu_lds[nb + n][2][t] = muout[mb + 2 * CC + t];
  }
  __syncthreads();

  // ---- phase 1: mu_mix from LDS-staged mu ----
  float mW[MNPT][3], sdot[MNPT];
  {
    float mV[MNPT][3];
    #pragma unroll
    for (int n = 0; n < MNPT; ++n)
      #pragma unroll
      for (int v = 0; v < 3; ++v) { mV[n][v] = 0.0f; mW[n][v] = 0.0f; }

    for (int c = 0; c < CC; c += 8) {
      float wv[8], ww[8];
      #pragma unroll
      for (int r = 0; r < 8; ++r) {
        const size_t row = (size_t)(c + r) * (2 * CC);
        wv[r] = Wmix[row + t];
        ww[r] = Wmix[row + CC + t];
      }
      #pragma unroll
      for (int n = 0; n < MNPT; ++n) {
        #pragma unroll
        for (int v = 0; v < 3; ++v) {
          const float4 m0 = *reinterpret_cast<const float4*>(&mu_lds[nb + n][v][c]);
          const float4 m1 = *reinterpret_cast<const float4*>(&mu_lds[nb + n][v][c + 4]);
          float a = mV[n][v], b = mW[n][v];
          a = fmaf(m0.x, wv[0], a); a = fmaf(m0.y, wv[1], a);
          a = fmaf(m0.z, wv[2], a); a = fmaf(m0.w, wv[3], a);
          a = fmaf(m1.x, wv[4], a); a = fmaf(m1.y, wv[5], a);
          a = fmaf(m1.z, wv[6], a); a = fmaf(m1.w, wv[7], a);
          b = fmaf(m0.x, ww[0], b); b = fmaf(m0.y, ww[1], b);
          b = fmaf(m0.z, ww[2], b); b = fmaf(m0.w, ww[3], b);
          b = fmaf(m1.x, ww[4], b); b = fmaf(m1.y, ww[5], b);
          b = fmaf(m1.z, ww[6], b); b = fmaf(m1.w, ww[7], b);
          mV[n][v] = a; mW[n][v] = b;
        }
      }
    }
    #pragma unroll
    for (int n = 0; n < MNPT; ++n) {
      const float ss = mV[n][0] * mV[n][0] + mV[n][1] * mV[n][1] + mV[n][2] * mV[n][2];
      vn_lds[nb + n][t] = sqrtf(ss + 1e-8f);
      sdot[n] = mV[n][0] * mW[n][0] + mV[n][1] * mW[n][1] + mV[n][2] * mW[n][2];
    }
  } // mV dies here
  __syncthreads();   // vn_lds visible

  // ---- phase 2: silu(ctx @ Wm1 + bm1) ----
  float acc[MNPT];
  {
    const float bv = bm1[t];
    #pragma unroll
    for (int n = 0; n < MNPT; ++n) acc[n] = bv;
  }
  // ctx first half: q, wave-uniform broadcast from global (L3-hot)
  for (int k = 0; k < CC; k += 8) {
    float w[8];
    #pragma unroll
    for (int r = 0; r < 8; ++r) w[r] = Wm1[(size_t)(k + r) * CC + t];
    #pragma unroll
    for (int n = 0; n < MNPT; ++n) {
      const float* qrow = qout + (size_t)(node0 + n) * CC + k;
      const float4 c0 = *reinterpret_cast<const float4*>(qrow);
      const float4 c1 = *reinterpret_cast<const float4*>(qrow + 4);
      acc[n] = fmaf(c0.x, w[0], acc[n]); acc[n] = fmaf(c0.y, w[1], acc[n]);
      acc[n] = fmaf(c0.z, w[2], acc[n]); acc[n] = fmaf(c0.w, w[3], acc[n]);
      acc[n] = fmaf(c1.x, w[4], acc[n]); acc[n] = fmaf(c1.y, w[5], acc[n]);
      acc[n] = fmaf(c1.z, w[6], acc[n]); acc[n] = fmaf(c1.w, w[7], acc[n]);
    }
  }
  // ctx second half: mu_Vn from LDS (broadcast)
  for (int k = 0; k < CC; k += 8) {
    float w[8];
    #pragma unroll
    for (int r = 0; r < 8; ++r) w[r] = Wm1[(size_t)(CC + k + r) * CC + t];
    #pragma unroll
    for (int n = 0; n < MNPT; ++n) {
      const float4 c0 = *reinterpret_cast<const float4*>(&vn_lds[nb + n][k]);
      const float4 c1 = *reinterpret_cast<const float4*>(&vn_lds[nb + n][k + 4]);
      acc[n] = fmaf(c0.x, w[0], acc[n]); acc[n] = fmaf(c0.y, w[1], acc[n]);
      acc[n] = fmaf(c0.z, w[2], acc[n]); acc[n] = fmaf(c0.w, w[3], acc[n]);
      acc[n] = fmaf(c1.x, w[4], acc[n]); acc[n] = fmaf(c1.y, w[5], acc[n]);
      acc[n] = fmaf(c1.z, w[6], acc[n]); acc[n] = fmaf(c1.w, w[7], acc[n]);
    }
  }
  #pragma unroll
  for (int n = 0; n < MNPT; ++n) {
    const float v = acc[n];
    h2_lds[nb + n][t] = v / (1.0f + expf(-v));
  }
  __syncthreads();   // h2 visible; all phase-2 broadcast reads of qout done

  // ---- phase 3: y = h2 @ Wm2 + bm2 ----
  float y0[MNPT], y1[MNPT], y2[MNPT];
  {
    const float bb0 = bm2[t], bb1 = bm2[CC + t], bb2 = bm2[2 * CC + t];
    #pragma unroll
    for (int n = 0; n < MNPT; ++n) { y0[n] = bb0; y1[n] = bb1; y2[n] = bb2; }
  }
  for (int k = 0; k < CC; k += 8) {
    float w0[8], w1[8], w2[8];
    #pragma unroll
    for (int r = 0; r < 8; ++r) {
      const size_t row = (size_t)(k + r) * TC;
      w0[r] = Wm2[row + t];
      w1[r] = Wm2[row + CC + t];
      w2[r] = Wm2[row + 2 * CC + t];
    }
    #pragma unroll
    for (int n = 0; n < MNPT; ++n) {
      const float4 h0 = *reinterpret_cast<const float4*>(&h2_lds[nb + n][k]);
      const float4 h1 = *reinterpret_cast<const float4*>(&h2_lds[nb + n][k + 4]);
      y0[n] = fmaf(h0.x, w0[0], y0[n]); y0[n] = fmaf(h0.y, w0[1], y0[n]);
      y0[n] = fmaf(h0.z, w0[2], y0[n]); y0[n] = fmaf(h0.w, w0[3], y0[n]);
      y0[n] = fmaf(h1.x, w0[4], y0[n]); y0[n] = fmaf(h1.y, w0[5], y0[n]);
      y0[n] = fmaf(h1.z, w0[6], y0[n]); y0[n] = fmaf(h1.w, w0[7], y0[n]);
      y1[n] = fmaf(h0.x, w1[0], y1[n]); y1[n] = fmaf(h0.y, w1[1], y1[n]);
      y1[n] = fmaf(h0.z, w1[2], y1[n]); y1[n] = fmaf(h0.w, w1[3], y1[n]);
      y1[n] = fmaf(h1.x, w1[4], y1[n]); y1[n] = fmaf(h1.y, w1[5], y1[n]);
      y1[n] = fmaf(h1.z, w1[6], y1[n]); y1[n] = fmaf(h1.w, w1[7], y1[n]);
      y2[n] = fmaf(h0.x, w2[0], y2[n]); y2[n] = fmaf(h0.y, w2[1], y2[n]);
      y2[n] = fmaf(h0.z, w2[2], y2[n]); y2[n] = fmaf(h0.w, w2[3], y2[n]);
      y2[n] = fmaf(h1.x, w2[4], y2[n]); y2[n] = fmaf(h1.y, w2[5], y2[n]);
      y2[n] = fmaf(h1.z, w2[6], y2[n]); y2[n] = fmaf(h1.w, w2[7], y2[n]);
    }
  }

  // ---- epilogue: q re-read coalesced (L3-hot), mu residual from LDS ----
  #pragma unroll
  for (int n = 0; n < MNPT; ++n) {
    const size_t qb = (size_t)(node0 + n) * CC;
    qout[qb + t] = qout[qb + t] + y0[n] + y2[n] * sdot[n];
    const size_t mb = (size_t)(node0 + n) * TC;
    muout[mb + t]          = mu_lds[nb + n][0][t] + y1[n] * mW[n][0];
    muout[mb + CC + t]     = mu_lds[nb + n][1][t] + y1[n] * mW[n][1];
    muout[mb + 2 * CC + t] = mu_lds[nb + n][2][t] + y1[n] * mW[n][2];
  }
}

// ---------------------------------------------------------------------------
extern "C" void kernel_launch(void* const* d_in, const int* in_sizes, int n_in,
                              void* d_out, int out_size, void* d_ws, size_t ws_size,
                              hipStream_t stream) {
  const float* q     = (const float*)d_in[0];
  const float* mu    = (const float*)d_in[1];
  const int*   eidx  = (const int*)d_in[2];
  const float* ew    = (const float*)d_in[3];
  const float* evers = (const float*)d_in[4];
  const float* eattr = (const float*)d_in[5];
  const float* Wf    = (const float*)d_in[6];
  const float* bf    = (const float*)d_in[7];
  const float* W1    = (const float*)d_in[8];
  const float* b1    = (const float*)d_in[9];
  const float* W2    = (const float*)d_in[10];
  const float* b2    = (const float*)d_in[11];
  const float* Wmix  = (const float*)d_in[12];
  const float* Wm1   = (const float*)d_in[13];
  const float* bm1   = (const float*)d_in[14];
  const float* Wm2   = (const float*)d_in[15];
  const float* bm2   = (const float*)d_in[16];

  float* out   = (float*)d_out;
  float* qout  = out;                                // [N, C]
  float* muout = out + (size_t)NNODES * CC;          // [N, 3, C]

  // workspace layout: packed | xh (fp16) | muh (fp16) | counts | offsets
  float*  packed  = (float*)d_ws;                           // [E*28] floats
  __half* xh      = (__half*)(packed + (size_t)NEDGES * PKF);   // [N*3C] halves
  __half* muh     = xh + (size_t)NNODES * TC;                   // [N*3C] halves
  int*    counts  = (int*)(muh + (size_t)NNODES * TC);      // [N]
  int*    offsets = counts + NNODES;                        // [N+1]
  const size_t need_packed =
      (size_t)NEDGES * PKF * 4 + (size_t)NNODES * TC * 2 * 2 +
      (2 * NNODES + 2) * 4 + 256;
  const bool use_packed = ws_size >= need_packed;

  if (use_packed) {
    zero_counts_kernel<<<(NNODES + 255) / 256, 256, 0, stream>>>(counts);
    hist_kernel<<<(NEDGES + 255) / 256, 256, 0, stream>>>(eidx, counts);
    scan_kernel<<<1, 512, 0, stream>>>(counts, offsets);
    pack_scatter_kernel<<<(NEDGES + 255) / 256, 256, 0, stream>>>(
        eidx, ew, evers, eattr, offsets, counts, packed);
    ctx_net_kernel<1><<<NNODES / CNPB, 128, 0, stream>>>(q, mu, W1, b1, W2, b2,
                                                         xh, muh);
    gather_packed_kernel<<<NNODES, GTH, 0, stream>>>(
        packed, Wf, bf, xh, muh, mu, q, offsets, qout, muout);
  } else {
    // fallback layout (xh fp16 | counts | offsets | edge_list); no muh --
    // ctx_net<0> skips the conversion, gather_list reads fp32 mu.
    __half* xf       = (__half*)d_ws;
    int*   countsf   = (int*)(xf + (size_t)NNODES * TC);
    int*   offsetsf  = countsf + NNODES;
    int*   edge_list = offsetsf + NNODES + 1;
    zero_counts_kernel<<<(NNODES + 255) / 256, 256, 0, stream>>>(countsf);
    hist_kernel<<<(NEDGES + 255) / 256, 256, 0, stream>>>(eidx, countsf);
    scan_kernel<<<1, 512, 0, stream>>>(countsf, offsetsf);
    scatter_kernel<<<(NEDGES + 255) / 256, 256, 0, stream>>>(eidx, offsetsf,
                                                             countsf, edge_list);
    ctx_net_kernel<0><<<NNODES / CNPB, 128, 0, stream>>>(q, mu, W1, b1, W2, b2,
                                                         xf, nullptr);
    gather_list_kernel<<<NNODES, GTH, 0, stream>>>(eidx, ew, evers, eattr,
                                                   Wf, bf, xf, mu, q,
                                                   offsetsf, edge_list,
                                                   qout, muout);
  }
  mix_kernel<<<NNODES / MNPB, 256, 0, stream>>>(Wmix, Wm1, bm1, Wm2, bm2,
                                                qout, muout);
}

// Round 11
// 597.688 us; speedup vs baseline: 1.0499x; 1.0499x over previous
//
#include <hip/hip_runtime.h>
#include <hip/hip_fp16.h>
#include <math.h>

#define NNODES 20000
#define NEDGES 320000
#define CC 128          // channels
#define TC 384          // 3*C
#define BB 20           // basis dim
#define RCUT_F 5.0f
#define PI_F 3.14159265358979323846f
#define PKF 28          // packed floats per edge (112 B, float4-aligned)

// ---------------------------------------------------------------------------
// CSR build: zero -> histogram -> single-block scan -> pack+scatter
// ---------------------------------------------------------------------------
__global__ __launch_bounds__(256) void zero_counts_kernel(int* __restrict__ counts) {
  const int i = blockIdx.x * 256 + threadIdx.x;
  if (i < NNODES) counts[i] = 0;
}

__global__ __launch_bounds__(256) void hist_kernel(const int* __restrict__ eidx,
                                                   int* __restrict__ counts) {
  const int e = blockIdx.x * 256 + threadIdx.x;
  if (e < NEDGES) atomicAdd(&counts[eidx[e]], 1);
}

__global__ __launch_bounds__(512) void scan_kernel(int* __restrict__ counts,
                                                   int* __restrict__ offsets) {
  __shared__ int sums[512];
  const int t = threadIdx.x;
  const int chunk = 40;                       // ceil(20000/512)
  const int lo = t * chunk;
  const int hi = min(lo + chunk, NNODES);
  int s = 0;
  for (int i = lo; i < hi; ++i) s += counts[i];
  sums[t] = s;
  __syncthreads();
  for (int d = 1; d < 512; d <<= 1) {
    const int other = (t >= d) ? sums[t - d] : 0;
    __syncthreads();
    sums[t] += other;
    __syncthreads();
  }
  int run = sums[t] - s;                      // exclusive prefix
  for (int i = lo; i < hi; ++i) {
    offsets[i] = run;
    run += counts[i];
    counts[i] = 0;                            // re-zero: reused as scatter cursor
  }
  if (hi == NNODES) offsets[NNODES] = run;    // == NEDGES
}

// packed[pos] = { j(bits), fc, v0, v1, v2, fc*attrs[0..19], pad[3] }
// r10 (kept): register-built row + 7x float4 stores (was 28 scalar stores)
// and 5x float4 eattr reads (rows are 80 B = 16B-aligned). ~9 us net win.
__global__ __launch_bounds__(256) void pack_scatter_kernel(
    const int* __restrict__ eidx, const float* __restrict__ ew,
    const float* __restrict__ evers, const float* __restrict__ eattr,
    const int* __restrict__ offsets, int* __restrict__ counts,
    float* __restrict__ packed) {
  const int e = blockIdx.x * 256 + threadIdx.x;
  if (e >= NEDGES) return;
  const int i = eidx[e];
  const int j = eidx[NEDGES + e];
  const int pos = offsets[i] + atomicAdd(&counts[i], 1);
  const float w = ew[e];
  const float fc = (w < RCUT_F)
      ? 0.5f * (cosf(PI_F * (1.0f / RCUT_F) * w) + 1.0f) : 0.0f;
  const float v0 = evers[(size_t)e * 3];
  const float v1 = evers[(size_t)e * 3 + 1];
  const float v2 = evers[(size_t)e * 3 + 2];
  const float4* ae4 = reinterpret_cast<const float4*>(eattr + (size_t)e * BB);
  const float4 a0 = ae4[0], a1 = ae4[1], a2 = ae4[2], a3 = ae4[3], a4 = ae4[4];
  float4* p4 = reinterpret_cast<float4*>(packed + (size_t)pos * PKF);
  p4[0] = make_float4(__int_as_float(j), fc, v0, v1);
  p4[1] = make_float4(v2, fc * a0.x, fc * a0.y, fc * a0.z);
  p4[2] = make_float4(fc * a0.w, fc * a1.x, fc * a1.y, fc * a1.z);
  p4[3] = make_float4(fc * a1.w, fc * a2.x, fc * a2.y, fc * a2.z);
  p4[4] = make_float4(fc * a2.w, fc * a3.x, fc * a3.y, fc * a3.z);
  p4[5] = make_float4(fc * a3.w, fc * a4.x, fc * a4.y, fc * a4.z);
  p4[6] = make_float4(fc * a4.w, 0.0f, 0.0f, 0.0f);
}

// fallback (no packing) scatter for small ws
__global__ __launch_bounds__(256) void scatter_kernel(const int* __restrict__ eidx,
                                                      const int* __restrict__ offsets,
                                                      int* __restrict__ counts,
                                                      int* __restrict__ edge_list) {
  const int e = blockIdx.x * 256 + threadIdx.x;
  if (e < NEDGES) {
    const int i = eidx[e];
    const int pos = offsets[i] + atomicAdd(&counts[i], 1);
    edge_list[pos] = e;
  }
}

// ---------------------------------------------------------------------------
// Context net: x = silu(q@W1 + b1) @ W2 + b2   [N, 3C] (fp16), plus OPTIONAL
// fused fp16 conversion of mu -> muh (CONVERT_MU=1; saves a launch).
// occ_pad: 12 KB LDS pin -> 20 KB total -> 4 waves/SIMD -> VGPR cap 128,
// no spill (allocator model verified r0-r3). r9: ctx_net was healthy anyway;
// pad kept as insurance, costs nothing (grid gives ~10 blk/CU regardless).
// ---------------------------------------------------------------------------
#define CNPB 8
template <int CONVERT_MU>
__global__ __launch_bounds__(128) void ctx_net_kernel(
    const float* __restrict__ q, const float* __restrict__ mu,
    const float* __restrict__ W1, const float* __restrict__ b1,
    const float* __restrict__ W2, const float* __restrict__ b2,
    __half* __restrict__ x, __half* __restrict__ muh) {
  __shared__ __align__(16) float q_lds[CNPB][CC];
  __shared__ __align__(16) float h_lds[CNPB][CC];
  __shared__ __align__(16) float occ_pad[3072];   // 12 KB occupancy pin
  const int t = threadIdx.x;
  const int node0 = blockIdx.x * CNPB;

  #pragma unroll
  for (int n = 0; n < CNPB; ++n)
    q_lds[n][t] = q[(size_t)(node0 + n) * CC + t];

  if (CONVERT_MU) {
    #pragma unroll
    for (int n = 0; n < CNPB; ++n) {
      const size_t mb = (size_t)(node0 + n) * TC;
      muh[mb + t]          = __float2half_rn(mu[mb + t]);
      muh[mb + CC + t]     = __float2half_rn(mu[mb + CC + t]);
      muh[mb + 2 * CC + t] = __float2half_rn(mu[mb + 2 * CC + t]);
    }
  }

  // keep occ_pad live (never taken at runtime; compiler can't prove it)
  if (blockIdx.x == 0x7FFFFFFFu) {
    occ_pad[t] = q[t];
    x[t] = __float2half_rn(occ_pad[t ^ 1]);
  }
  __syncthreads();

  float acc[CNPB];
  {
    const float bv = b1[t];
    #pragma unroll
    for (int n = 0; n < CNPB; ++n) acc[n] = bv;
  }
  for (int k = 0; k < CC; k += 8) {
    float w[8];
    #pragma unroll
    for (int r = 0; r < 8; ++r) w[r] = W1[(size_t)(k + r) * CC + t];
    #pragma unroll
    for (int n = 0; n < CNPB; ++n) {
      const float4 q0 = *reinterpret_cast<const float4*>(&q_lds[n][k]);
      const float4 q1 = *reinterpret_cast<const float4*>(&q_lds[n][k + 4]);
      acc[n] = fmaf(q0.x, w[0], acc[n]); acc[n] = fmaf(q0.y, w[1], acc[n]);
      acc[n] = fmaf(q0.z, w[2], acc[n]); acc[n] = fmaf(q0.w, w[3], acc[n]);
      acc[n] = fmaf(q1.x, w[4], acc[n]); acc[n] = fmaf(q1.y, w[5], acc[n]);
      acc[n] = fmaf(q1.z, w[6], acc[n]); acc[n] = fmaf(q1.w, w[7], acc[n]);
    }
  }
  #pragma unroll
  for (int n = 0; n < CNPB; ++n) {
    const float v = acc[n];
    h_lds[n][t] = v / (1.0f + expf(-v));
  }
  __syncthreads();

  float y0[CNPB], y1[CNPB], y2[CNPB];
  {
    const float bb0 = b2[t], bb1 = b2[CC + t], bb2 = b2[2 * CC + t];
    #pragma unroll
    for (int n = 0; n < CNPB; ++n) { y0[n] = bb0; y1[n] = bb1; y2[n] = bb2; }
  }
  for (int k = 0; k < CC; k += 8) {
    float w0[8], w1[8], w2[8];
    #pragma unroll
    for (int r = 0; r < 8; ++r) {
      const size_t row = (size_t)(k + r) * TC;
      w0[r] = W2[row + t];
      w1[r] = W2[row + CC + t];
      w2[r] = W2[row + 2 * CC + t];
    }
    #pragma unroll
    for (int n = 0; n < CNPB; ++n) {
      const float4 h0 = *reinterpret_cast<const float4*>(&h_lds[n][k]);
      const float4 h1 = *reinterpret_cast<const float4*>(&h_lds[n][k + 4]);
      y0[n] = fmaf(h0.x, w0[0], y0[n]); y0[n] = fmaf(h0.y, w0[1], y0[n]);
      y0[n] = fmaf(h0.z, w0[2], y0[n]); y0[n] = fmaf(h0.w, w0[3], y0[n]);
      y0[n] = fmaf(h1.x, w0[4], y0[n]); y0[n] = fmaf(h1.y, w0[5], y0[n]);
      y0[n] = fmaf(h1.z, w0[6], y0[n]); y0[n] = fmaf(h1.w, w0[7], y0[n]);
      y1[n] = fmaf(h0.x, w1[0], y1[n]); y1[n] = fmaf(h0.y, w1[1], y1[n]);
      y1[n] = fmaf(h0.z, w1[2], y1[n]); y1[n] = fmaf(h0.w, w1[3], y1[n]);
      y1[n] = fmaf(h1.x, w1[4], y1[n]); y1[n] = fmaf(h1.y, w1[5], y1[n]);
      y1[n] = fmaf(h1.z, w1[6], y1[n]); y1[n] = fmaf(h1.w, w1[7], y1[n]);
      y2[n] = fmaf(h0.x, w2[0], y2[n]); y2[n] = fmaf(h0.y, w2[1], y2[n]);
      y2[n] = fmaf(h0.z, w2[2], y2[n]); y2[n] = fmaf(h0.w, w2[3], y2[n]);
      y2[n] = fmaf(h1.x, w2[4], y2[n]); y2[n] = fmaf(h1.y, w2[5], y2[n]);
      y2[n] = fmaf(h1.z, w2[6], y2[n]); y2[n] = fmaf(h1.w, w2[7], y2[n]);
    }
  }
  #pragma unroll
  for (int n = 0; n < CNPB; ++n) {
    const size_t base = (size_t)(node0 + n) * TC;
    x[base + t]          = __float2half_rn(y0[n]);
    x[base + CC + t]     = __float2half_rn(y1[n]);
    x[base + 2 * CC + t] = __float2half_rn(y2[n]);
  }
}

// ---------------------------------------------------------------------------
// Gather (packed path): one block of 384 threads per node; thread c owns
// filter column c (weights in 20 regs). EXACT r5-verified form (177 us).
// Ledger (all A/B'd against this structure, 6 attempts):
//   r3 x2 fp32 = 186 | r4 manual rotate = 294 (vmcnt(0) drains)
//   r5 x2 fp16 = 177 | r6 x4 unroll = 251 (regs can't hold 4 chains)
//   r7 persistent-1280 = 237 (barrier serialization, no oversubscription)
//   r8 muh4 interleave = 200 (FETCH +39MB, grp2 wasn't critical)
// => this is the floor of this structure. DO NOT touch.
// ---------------------------------------------------------------------------
#define GTH 384

struct EdgeRegs { float4 h0, h1, h2, h3, h4, h5, h6; };

__device__ __forceinline__ EdgeRegs load_edge(const float4* __restrict__ p4,
                                              int k) {
  const float4* p = p4 + (size_t)k * (PKF / 4);
  EdgeRegs E;
  E.h0 = p[0]; E.h1 = p[1]; E.h2 = p[2]; E.h3 = p[3];
  E.h4 = p[4]; E.h5 = p[5]; E.h6 = p[6];
  return E;
}

__device__ __forceinline__ float filter_ws(const EdgeRegs& E,
                                           const float* wreg, float bfc) {
  float ws = E.h0.y * bfc;                    // fc * bf[c]
  ws = fmaf(E.h1.y, wreg[0], ws);  ws = fmaf(E.h1.z, wreg[1], ws);
  ws = fmaf(E.h1.w, wreg[2], ws);  ws = fmaf(E.h2.x, wreg[3], ws);
  ws = fmaf(E.h2.y, wreg[4], ws);  ws = fmaf(E.h2.z, wreg[5], ws);
  ws = fmaf(E.h2.w, wreg[6], ws);  ws = fmaf(E.h3.x, wreg[7], ws);
  ws = fmaf(E.h3.y, wreg[8], ws);  ws = fmaf(E.h3.z, wreg[9], ws);
  ws = fmaf(E.h3.w, wreg[10], ws); ws = fmaf(E.h4.x, wreg[11], ws);
  ws = fmaf(E.h4.y, wreg[12], ws); ws = fmaf(E.h4.z, wreg[13], ws);
  ws = fmaf(E.h4.w, wreg[14], ws); ws = fmaf(E.h5.x, wreg[15], ws);
  ws = fmaf(E.h5.y, wreg[16], ws); ws = fmaf(E.h5.z, wreg[17], ws);
  ws = fmaf(E.h5.w, wreg[18], ws); ws = fmaf(E.h6.x, wreg[19], ws);
  return ws;
}

__global__ __launch_bounds__(GTH) void gather_packed_kernel(
    const float* __restrict__ packed,
    const float* __restrict__ Wf, const float* __restrict__ bf,
    const __half* __restrict__ xh, const __half* __restrict__ muh,
    const float* __restrict__ mu_in,
    const float* __restrict__ q_in, const int* __restrict__ offsets,
    float* __restrict__ qout, float* __restrict__ muout) {
  __shared__ float red[3][CC];
  const int c = threadIdx.x;
  const int i = blockIdx.x;
  const int grp = c >> 7;          // wave-uniform
  const int ch = c & 127;

  float wreg[BB];
  #pragma unroll
  for (int b = 0; b < BB; ++b) wreg[b] = Wf[b * TC + c];
  const float bfc = bf[c];

  const float4* p4 = reinterpret_cast<const float4*>(packed);
  const int start = offsets[i];
  const int end = offsets[i + 1];
  float a0 = 0.f, a1 = 0.f, a2 = 0.f;

  int k = start;
  for (; k + 1 < end; k += 2) {
    const EdgeRegs A = load_edge(p4, k);
    const EdgeRegs B = load_edge(p4, k + 1);
    const int jA = __float_as_int(A.h0.x);
    const int jB = __float_as_int(B.h0.x);
    const float xA = __half2float(xh[(size_t)jA * TC + c]);
    const float xB = __half2float(xh[(size_t)jB * TC + c]);
    float muA0, muA1, muA2, muB0, muB1, muB2;
    if (grp == 2) {
      const __half* mA = muh + (size_t)jA * TC + ch;
      const __half* mB = muh + (size_t)jB * TC + ch;
      muA0 = __half2float(mA[0]);
      muA1 = __half2float(mA[CC]);
      muA2 = __half2float(mA[2 * CC]);
      muB0 = __half2float(mB[0]);
      muB1 = __half2float(mB[CC]);
      muB2 = __half2float(mB[2 * CC]);
    }
    const float wsA = filter_ws(A, wreg, bfc);
    const float wsB = filter_ws(B, wreg, bfc);
    const float xvA = xA * wsA;
    const float xvB = xB * wsB;
    if (grp == 0) {
      a0 += xvA + xvB;
    } else if (grp == 1) {
      a0 = fmaf(xvA, A.h0.z, fmaf(xvB, B.h0.z, a0));
      a1 = fmaf(xvA, A.h0.w, fmaf(xvB, B.h0.w, a1));
      a2 = fmaf(xvA, A.h1.x, fmaf(xvB, B.h1.x, a2));
    } else {
      a0 = fmaf(xvA, muA0, fmaf(xvB, muB0, a0));
      a1 = fmaf(xvA, muA1, fmaf(xvB, muB1, a1));
      a2 = fmaf(xvA, muA2, fmaf(xvB, muB2, a2));
    }
  }
  if (k < end) {
    const EdgeRegs A = load_edge(p4, k);
    const int jA = __float_as_int(A.h0.x);
    const float xA = __half2float(xh[(size_t)jA * TC + c]);
    const float wsA = filter_ws(A, wreg, bfc);
    const float xvA = xA * wsA;
    if (grp == 0) {
      a0 += xvA;
    } else if (grp == 1) {
      a0 = fmaf(xvA, A.h0.z, a0);
      a1 = fmaf(xvA, A.h0.w, a1);
      a2 = fmaf(xvA, A.h1.x, a2);
    } else {
      const __half* mA = muh + (size_t)jA * TC + ch;
      a0 = fmaf(xvA, __half2float(mA[0]), a0);
      a1 = fmaf(xvA, __half2float(mA[CC]), a1);
      a2 = fmaf(xvA, __half2float(mA[2 * CC]), a2);
    }
  }

  if (grp == 1) { red[0][ch] = a0; red[1][ch] = a1; red[2][ch] = a2; }
  __syncthreads();

  if (grp == 0) {
    qout[(size_t)i * CC + ch] = q_in[(size_t)i * CC + ch] + a0;
  } else if (grp == 2) {
    const size_t mb = (size_t)i * TC;
    muout[mb + ch]          = mu_in[mb + ch]          + red[0][ch] + a0;
    muout[mb + CC + ch]     = mu_in[mb + CC + ch]     + red[1][ch] + a1;
    muout[mb + 2 * CC + ch] = mu_in[mb + 2 * CC + ch] + red[2][ch] + a2;
  }
}

// fallback gather (edge_list indirection) for small ws
__global__ __launch_bounds__(GTH) void gather_list_kernel(
    const int* __restrict__ eidx, const float* __restrict__ ew,
    const float* __restrict__ evers, const float* __restrict__ eattr,
    const float* __restrict__ Wf, const float* __restrict__ bf,
    const __half* __restrict__ xh, const float* __restrict__ mu_in,
    const float* __restrict__ q_in,
    const int* __restrict__ offsets, const int* __restrict__ edge_list,
    float* __restrict__ qout, float* __restrict__ muout) {
  __shared__ float red[3][CC];
  const int c = threadIdx.x;
  const int i = blockIdx.x;
  const int grp = c >> 7;
  const int ch = c & 127;
  float wreg[BB];
  #pragma unroll
  for (int b = 0; b < BB; ++b) wreg[b] = Wf[b * TC + c];
  const float bfc = bf[c];
  const int start = offsets[i];
  const int end = offsets[i + 1];
  float a0 = 0.f, a1 = 0.f, a2 = 0.f;
  for (int k = start; k < end; ++k) {
    const int e = edge_list[k];
    const int j = eidx[NEDGES + e];
    const float w = ew[e];
    const float fc = (w < RCUT_F)
        ? 0.5f * (cosf(PI_F * (1.0f / RCUT_F) * w) + 1.0f) : 0.0f;
    const float2* ae2 = reinterpret_cast<const float2*>(eattr + (size_t)e * BB);
    float wsum = bfc;
    #pragma unroll
    for (int b = 0; b < BB / 2; ++b) {
      const float2 a = ae2[b];
      wsum = fmaf(a.x, wreg[2 * b], wsum);
      wsum = fmaf(a.y, wreg[2 * b + 1], wsum);
    }
    wsum *= fc;
    const float xv = __half2float(xh[(size_t)j * TC + c]) * wsum;
    if (grp == 0) {
      a0 += xv;
    } else if (grp == 1) {
      const float v0 = evers[(size_t)e * 3];
      const float v1 = evers[(size_t)e * 3 + 1];
      const float v2 = evers[(size_t)e * 3 + 2];
      a0 = fmaf(xv, v0, a0); a1 = fmaf(xv, v1, a1); a2 = fmaf(xv, v2, a2);
    } else {
      const float* muj = mu_in + (size_t)j * TC + ch;
      a0 = fmaf(xv, muj[0], a0);
      a1 = fmaf(xv, muj[CC], a1);
      a2 = fmaf(xv, muj[2 * CC], a2);
    }
  }
  if (grp == 1) { red[0][ch] = a0; red[1][ch] = a1; red[2][ch] = a2; }
  __syncthreads();
  if (grp == 0) {
    qout[(size_t)i * CC + ch] = q_in[(size_t)i * CC + ch] + a0;
  } else if (grp == 2) {
    const size_t mb = (size_t)i * TC;
    muout[mb + ch]          = mu_in[mb + ch]          + red[0][ch] + a0;
    muout[mb + CC + ch]     = mu_in[mb + CC + ch]     + red[1][ch] + a1;
    muout[mb + 2 * CC + ch] = mu_in[mb + 2 * CC + ch] + red[2][ch] + a2;
  }
}

// ---------------------------------------------------------------------------
// Mixing kernel (REVERTED to r3/r9-verified form): 8 nodes, 128 threads,
// 20 KB LDS. Mix ledger: r0 24KB/8n=195 | r3 20KB/8n~165 (sub-top-5) |
// r10 40KB/16n=201 (4 blk/CU -> occupancy 20%, latency-hiding starved --
// same failure mode as r7's persistent gather; weight-L1-broadcast theory
// refuted: mix is latency-bound, not weight-BW-bound).
// VGPR-allocator model (verified r0-r3): cap = f(LDS-implied occupancy).
// 20KB -> 8 blk/CU = 4 waves/SIMD -> cap 128 >= ~90 needed => no spill.
// ---------------------------------------------------------------------------
#define MNPB 8
__global__ __launch_bounds__(128) void mix_kernel(
    const float* __restrict__ Wmix, const float* __restrict__ Wm1,
    const float* __restrict__ bm1, const float* __restrict__ Wm2,
    const float* __restrict__ bm2, float* __restrict__ qout,
    float* __restrict__ muout) {
  __shared__ __align__(16) float mu_lds[MNPB][3][CC];   // 12 KB
  __shared__ __align__(16) float vn_lds[MNPB][CC];      // 4 KB
  __shared__ __align__(16) float h2_lds[MNPB][CC];      // 4 KB

  const int t = threadIdx.x;
  const int node0 = blockIdx.x * MNPB;

  #pragma unroll
  for (int n = 0; n < MNPB; ++n) {
    const size_t mb = (size_t)(node0 + n) * TC;
    mu_lds[n][0][t] = muout[mb + t];
    mu_lds[n][1][t] = muout[mb + CC + t];
    mu_lds[n][2][t] = muout[mb + 2 * CC + t];
  }
  __syncthreads();

  // ---- phase 1: mu_mix from LDS-staged mu ----
  float mW[MNPB][3], sdot[MNPB];
  {
    float mV[MNPB][3];
    #pragma unroll
    for (int n = 0; n < MNPB; ++n)
      #pragma unroll
      for (int v = 0; v < 3; ++v) { mV[n][v] = 0.0f; mW[n][v] = 0.0f; }

    for (int c = 0; c < CC; c += 8) {
      float wv[8], ww[8];
      #pragma unroll
      for (int r = 0; r < 8; ++r) {
        const size_t row = (size_t)(c + r) * (2 * CC);
        wv[r] = Wmix[row + t];
        ww[r] = Wmix[row + CC + t];
      }
      #pragma unroll
      for (int n = 0; n < MNPB; ++n) {
        #pragma unroll
        for (int v = 0; v < 3; ++v) {
          const float4 m0 = *reinterpret_cast<const float4*>(&mu_lds[n][v][c]);
          const float4 m1 = *reinterpret_cast<const float4*>(&mu_lds[n][v][c + 4]);
          float a = mV[n][v], b = mW[n][v];
          a = fmaf(m0.x, wv[0], a); a = fmaf(m0.y, wv[1], a);
          a = fmaf(m0.z, wv[2], a); a = fmaf(m0.w, wv[3], a);
          a = fmaf(m1.x, wv[4], a); a = fmaf(m1.y, wv[5], a);
          a = fmaf(m1.z, wv[6], a); a = fmaf(m1.w, wv[7], a);
          b = fmaf(m0.x, ww[0], b); b = fmaf(m0.y, ww[1], b);
          b = fmaf(m0.z, ww[2], b); b = fmaf(m0.w, ww[3], b);
          b = fmaf(m1.x, ww[4], b); b = fmaf(m1.y, ww[5], b);
          b = fmaf(m1.z, ww[6], b); b = fmaf(m1.w, ww[7], b);
          mV[n][v] = a; mW[n][v] = b;
        }
      }
    }
    #pragma unroll
    for (int n = 0; n < MNPB; ++n) {
      const float ss = mV[n][0] * mV[n][0] + mV[n][1] * mV[n][1] + mV[n][2] * mV[n][2];
      vn_lds[n][t] = sqrtf(ss + 1e-8f);
      sdot[n] = mV[n][0] * mW[n][0] + mV[n][1] * mW[n][1] + mV[n][2] * mW[n][2];
    }
  } // mV dies here
  __syncthreads();   // vn_lds visible

  // ---- phase 2: silu(ctx @ Wm1 + bm1) ----
  float acc[MNPB];
  {
    const float bv = bm1[t];
    #pragma unroll
    for (int n = 0; n < MNPB; ++n) acc[n] = bv;
  }
  // ctx first half: q, wave-uniform broadcast from global (L3-hot)
  for (int k = 0; k < CC; k += 8) {
    float w[8];
    #pragma unroll
    for (int r = 0; r < 8; ++r) w[r] = Wm1[(size_t)(k + r) * CC + t];
    #pragma unroll
    for (int n = 0; n < MNPB; ++n) {
      const float* qrow = qout + (size_t)(node0 + n) * CC + k;
      const float4 c0 = *reinterpret_cast<const float4*>(qrow);
      const float4 c1 = *reinterpret_cast<const float4*>(qrow + 4);
      acc[n] = fmaf(c0.x, w[0], acc[n]); acc[n] = fmaf(c0.y, w[1], acc[n]);
      acc[n] = fmaf(c0.z, w[2], acc[n]); acc[n] = fmaf(c0.w, w[3], acc[n]);
      acc[n] = fmaf(c1.x, w[4], acc[n]); acc[n] = fmaf(c1.y, w[5], acc[n]);
      acc[n] = fmaf(c1.z, w[6], acc[n]); acc[n] = fmaf(c1.w, w[7], acc[n]);
    }
  }
  // ctx second half: mu_Vn from LDS (broadcast)
  for (int k = 0; k < CC; k += 8) {
    float w[8];
    #pragma unroll
    for (int r = 0; r < 8; ++r) w[r] = Wm1[(size_t)(CC + k + r) * CC + t];
    #pragma unroll
    for (int n = 0; n < MNPB; ++n) {
      const float4 c0 = *reinterpret_cast<const float4*>(&vn_lds[n][k]);
      const float4 c1 = *reinterpret_cast<const float4*>(&vn_lds[n][k + 4]);
      acc[n] = fmaf(c0.x, w[0], acc[n]); acc[n] = fmaf(c0.y, w[1], acc[n]);
      acc[n] = fmaf(c0.z, w[2], acc[n]); acc[n] = fmaf(c0.w, w[3], acc[n]);
      acc[n] = fmaf(c1.x, w[4], acc[n]); acc[n] = fmaf(c1.y, w[5], acc[n]);
      acc[n] = fmaf(c1.z, w[6], acc[n]); acc[n] = fmaf(c1.w, w[7], acc[n]);
    }
  }
  #pragma unroll
  for (int n = 0; n < MNPB; ++n) {
    const float v = acc[n];
    h2_lds[n][t] = v / (1.0f + expf(-v));
  }
  __syncthreads();   // h2 visible; all phase-2 broadcast reads of qout done

  // ---- phase 3: y = h2 @ Wm2 + bm2 ----
  float y0[MNPB], y1[MNPB], y2[MNPB];
  {
    const float bb0 = bm2[t], bb1 = bm2[CC + t], bb2 = bm2[2 * CC + t];
    #pragma unroll
    for (int n = 0; n < MNPB; ++n) { y0[n] = bb0; y1[n] = bb1; y2[n] = bb2; }
  }
  for (int k = 0; k < CC; k += 8) {
    float w0[8], w1[8], w2[8];
    #pragma unroll
    for (int r = 0; r < 8; ++r) {
      const size_t row = (size_t)(k + r) * TC;
      w0[r] = Wm2[row + t];
      w1[r] = Wm2[row + CC + t];
      w2[r] = Wm2[row + 2 * CC + t];
    }
    #pragma unroll
    for (int n = 0; n < MNPB; ++n) {
      const float4 h0 = *reinterpret_cast<const float4*>(&h2_lds[n][k]);
      const float4 h1 = *reinterpret_cast<const float4*>(&h2_lds[n][k + 4]);
      y0[n] = fmaf(h0.x, w0[0], y0[n]); y0[n] = fmaf(h0.y, w0[1], y0[n]);
      y0[n] = fmaf(h0.z, w0[2], y0[n]); y0[n] = fmaf(h0.w, w0[3], y0[n]);
      y0[n] = fmaf(h1.x, w0[4], y0[n]); y0[n] = fmaf(h1.y, w0[5], y0[n]);
      y0[n] = fmaf(h1.z, w0[6], y0[n]); y0[n] = fmaf(h1.w, w0[7], y0[n]);
      y1[n] = fmaf(h0.x, w1[0], y1[n]); y1[n] = fmaf(h0.y, w1[1], y1[n]);
      y1[n] = fmaf(h0.z, w1[2], y1[n]); y1[n] = fmaf(h0.w, w1[3], y1[n]);
      y1[n] = fmaf(h1.x, w1[4], y1[n]); y1[n] = fmaf(h1.y, w1[5], y1[n]);
      y1[n] = fmaf(h1.z, w1[6], y1[n]); y1[n] = fmaf(h1.w, w1[7], y1[n]);
      y2[n] = fmaf(h0.x, w2[0], y2[n]); y2[n] = fmaf(h0.y, w2[1], y2[n]);
      y2[n] = fmaf(h0.z, w2[2], y2[n]); y2[n] = fmaf(h0.w, w2[3], y2[n]);
      y2[n] = fmaf(h1.x, w2[4], y2[n]); y2[n] = fmaf(h1.y, w2[5], y2[n]);
      y2[n] = fmaf(h1.z, w2[6], y2[n]); y2[n] = fmaf(h1.w, w2[7], y2[n]);
    }
  }

  // ---- epilogue: q re-read coalesced (L3-hot), mu residual from LDS ----
  #pragma unroll
  for (int n = 0; n < MNPB; ++n) {
    const size_t qb = (size_t)(node0 + n) * CC;
    qout[qb + t] = qout[qb + t] + y0[n] + y2[n] * sdot[n];
    const size_t mb = (size_t)(node0 + n) * TC;
    muout[mb + t]          = mu_lds[n][0][t] + y1[n] * mW[n][0];
    muout[mb + CC + t]     = mu_lds[n][1][t] + y1[n] * mW[n][1];
    muout[mb + 2 * CC + t] = mu_lds[n][2][t] + y1[n] * mW[n][2];
  }
}

// ---------------------------------------------------------------------------
extern "C" void kernel_launch(void* const* d_in, const int* in_sizes, int n_in,
                              void* d_out, int out_size, void* d_ws, size_t ws_size,
                              hipStream_t stream) {
  const float* q     = (const float*)d_in[0];
  const float* mu    = (const float*)d_in[1];
  const int*   eidx  = (const int*)d_in[2];
  const float* ew    = (const float*)d_in[3];
  const float* evers = (const float*)d_in[4];
  const float* eattr = (const float*)d_in[5];
  const float* Wf    = (const float*)d_in[6];
  const float* bf    = (const float*)d_in[7];
  const float* W1    = (const float*)d_in[8];
  const float* b1    = (const float*)d_in[9];
  const float* W2    = (const float*)d_in[10];
  const float* b2    = (const float*)d_in[11];
  const float* Wmix  = (const float*)d_in[12];
  const float* Wm1   = (const float*)d_in[13];
  const float* bm1   = (const float*)d_in[14];
  const float* Wm2   = (const float*)d_in[15];
  const float* bm2   = (const float*)d_in[16];

  float* out   = (float*)d_out;
  float* qout  = out;                                // [N, C]
  float* muout = out + (size_t)NNODES * CC;          // [N, 3, C]

  // workspace layout: packed | xh (fp16) | muh (fp16) | counts | offsets
  float*  packed  = (float*)d_ws;                           // [E*28] floats
  __half* xh      = (__half*)(packed + (size_t)NEDGES * PKF);   // [N*3C] halves
  __half* muh     = xh + (size_t)NNODES * TC;                   // [N*3C] halves
  int*    counts  = (int*)(muh + (size_t)NNODES * TC);      // [N]
  int*    offsets = counts + NNODES;                        // [N+1]
  const size_t need_packed =
      (size_t)NEDGES * PKF * 4 + (size_t)NNODES * TC * 2 * 2 +
      (2 * NNODES + 2) * 4 + 256;
  const bool use_packed = ws_size >= need_packed;

  if (use_packed) {
    zero_counts_kernel<<<(NNODES + 255) / 256, 256, 0, stream>>>(counts);
    hist_kernel<<<(NEDGES + 255) / 256, 256, 0, stream>>>(eidx, counts);
    scan_kernel<<<1, 512, 0, stream>>>(counts, offsets);
    pack_scatter_kernel<<<(NEDGES + 255) / 256, 256, 0, stream>>>(
        eidx, ew, evers, eattr, offsets, counts, packed);
    ctx_net_kernel<1><<<NNODES / CNPB, 128, 0, stream>>>(q, mu, W1, b1, W2, b2,
                                                         xh, muh);
    gather_packed_kernel<<<NNODES, GTH, 0, stream>>>(
        packed, Wf, bf, xh, muh, mu, q, offsets, qout, muout);
  } else {
    // fallback layout (xh fp16 | counts | offsets | edge_list); no muh --
    // ctx_net<0> skips the conversion, gather_list reads fp32 mu.
    __half* xf       = (__half*)d_ws;
    int*   countsf   = (int*)(xf + (size_t)NNODES * TC);
    int*   offsetsf  = countsf + NNODES;
    int*   edge_list = offsetsf + NNODES + 1;
    zero_counts_kernel<<<(NNODES + 255) / 256, 256, 0, stream>>>(countsf);
    hist_kernel<<<(NEDGES + 255) / 256, 256, 0, stream>>>(eidx, countsf);
    scan_kernel<<<1, 512, 0, stream>>>(countsf, offsetsf);
    scatter_kernel<<<(NEDGES + 255) / 256, 256, 0, stream>>>(eidx, offsetsf,
                                                             countsf, edge_list);
    ctx_net_kernel<0><<<NNODES / CNPB, 128, 0, stream>>>(q, mu, W1, b1, W2, b2,
                                                         xf, nullptr);
    gather_list_kernel<<<NNODES, GTH, 0, stream>>>(eidx, ew, evers, eattr,
                                                   Wf, bf, xf, mu, q,
                                                   offsetsf, edge_list,
                                                   qout, muout);
  }
  mix_kernel<<<NNODES / MNPB, 128, 0, stream>>>(Wmix, Wm1, bm1, Wm2, bm2,
                                                qout, muout);
}